// Round 12
// baseline (296.411 us; speedup 1.0000x reference)
//
#include <hip/hip_runtime.h>

#define NTOK 16384
#define DIM 512
#define NTAU 4

typedef __attribute__((ext_vector_type(4))) float f32x4;
typedef __attribute__((ext_vector_type(8))) short bf16x8;   // 8 bf16 in 4 VGPRs
typedef __attribute__((ext_vector_type(4))) unsigned short u16x4;
typedef __attribute__((ext_vector_type(8))) unsigned short u16x8;
typedef unsigned int u32;

__device__ inline unsigned short f2bf(float f) {
    union { float f; unsigned int u; } v; v.f = f;
    unsigned int u = v.u + 0x7FFFu + ((v.u >> 16) & 1u);  // RNE
    return (unsigned short)(u >> 16);
}

__device__ inline void bf8_to_f32(u16x8 h, f32x4& a, f32x4& b) {
    union { unsigned int u; float f; } t;
#pragma unroll
    for (int e = 0; e < 4; e++) { t.u = ((unsigned int)h[e]) << 16; a[e] = t.f; }
#pragma unroll
    for (int e = 0; e < 4; e++) { t.u = ((unsigned int)h[4 + e]) << 16; b[e] = t.f; }
}

#define NTLOAD4(p) __builtin_nontemporal_load((const f32x4*)(p))

// async global -> LDS, 16 bytes per lane. LDS dest: wave-uniform base + lane*16.
__device__ __forceinline__ void gload16(const void* g, void* l) {
    __builtin_amdgcn_global_load_lds((const __attribute__((address_space(1))) u32*)g,
                                     (__attribute__((address_space(3))) u32*)l, 16, 0, 0);
}

// ---------------- K0a: fp32 -> bf16 convert (two 512x512 next-weights) ----------
__global__ void convert2(const float* __restrict__ a, const float* __restrict__ b,
                         unsigned short* __restrict__ oa, unsigned short* __restrict__ ob) {
    int i = blockIdx.x * 256 + threadIdx.x;   // 0..131071 (x4 units)
    const float* s = (i < 65536) ? a : b;
    unsigned short* t = (i < 65536) ? oa : ob;
    int off = (i < 65536) ? i : i - 65536;
    f32x4 v = ((const f32x4*)s)[off];
    u16x4 o;
    o[0] = f2bf(v[0]); o[1] = f2bf(v[1]); o[2] = f2bf(v[2]); o[3] = f2bf(v[3]);
    ((u16x4*)t)[off] = o;
}

// ---------------- K0b: permute-convert big W into MFMA B-frag order ----------
// W'[g][j16][ks][lane][e] = W[g*512 + j16*16 + (lane&15)][ks*32 + (lane>>4)*8 + e]
// so a wave's B-frag load is base + lane*16B (coalesced 1KB).
__global__ void convert_perm(const float* __restrict__ Wt, const float* __restrict__ Ws,
                             unsigned short* __restrict__ Wtp, unsigned short* __restrict__ Wsp) {
    int i = blockIdx.x * 256 + threadIdx.x;       // 0..196607
    const float* src = (i < 98304) ? Wt : Ws;
    unsigned short* dst = (i < 98304) ? Wtp : Wsp;
    int r = (i < 98304) ? i : i - 98304;          // 0..98303
    int g    = r >> 15;
    int rem  = r & 32767;
    int j16  = rem >> 10;
    int rem2 = rem & 1023;
    int ks   = rem2 >> 6;
    int lane = rem2 & 63;
    int row = g * 512 + j16 * 16 + (lane & 15);
    int col = ks * 32 + (lane >> 4) * 8;
    const float* sp = src + (size_t)row * DIM + col;
    u16x8 o;
#pragma unroll
    for (int e = 0; e < 8; e++) o[e] = f2bf(sp[e]);
    *(u16x8*)(dst + (size_t)r * 8) = o;
}

// ---------------- K1: BOTH next-GEMMs in one launch (1024 blocks) ----------------
__global__ __launch_bounds__(256, 2) void gemm_next2(
    const float* __restrict__ T_t, const float* __restrict__ S_t,
    const unsigned short* __restrict__ Wtn, const unsigned short* __restrict__ Wsn,
    const float* __restrict__ btn, const float* __restrict__ bsn,
    unsigned short* __restrict__ t_next, unsigned short* __restrict__ s_next)
{
    __shared__ unsigned short lA[128][40];
    __shared__ unsigned short lB[128][40];
    const int tid = threadIdx.x;
    const int id = blockIdx.x;                    // 0..1023
    const int xcd = id & 7;
    const int rest = id >> 3;                     // 0..127
    const int mat = rest & 1;
    const int idx = rest >> 1;                    // 0..63
    const float* A = mat ? S_t : T_t;
    const unsigned short* W = mat ? Wsn : Wtn;
    const float* bias = mat ? bsn : btn;
    unsigned short* out = mat ? s_next : t_next;
    const int m0 = (xcd * 16 + (idx >> 2)) * 128;
    const int n0 = (idx & 3) * 128;
    const int lane = tid & 63;
    const int w = tid >> 6;
    const int wr = w >> 1, wc = w & 1;

    f32x4 acc[4][4];
#pragma unroll
    for (int i = 0; i < 4; i++)
#pragma unroll
        for (int j = 0; j < 4; j++) acc[i][j] = (f32x4){0.f, 0.f, 0.f, 0.f};

    const int arow = tid >> 3;
    const int acol = (tid & 7) * 4;
    const int brow = tid >> 2;
    const int bcol = (tid & 3) * 8;

    for (int k0 = 0; k0 < DIM; k0 += 32) {
#pragma unroll
        for (int i = 0; i < 4; i++) {
            int r = arow + 32 * i;
            f32x4 v = *(const f32x4*)(A + (size_t)(m0 + r) * DIM + k0 + acol);
            u16x4 o;
            o[0] = f2bf(v[0]); o[1] = f2bf(v[1]); o[2] = f2bf(v[2]); o[3] = f2bf(v[3]);
            *(u16x4*)&lA[r][acol] = o;
        }
#pragma unroll
        for (int i = 0; i < 2; i++) {
            int r = brow + 64 * i;
            u16x8 v = *(const u16x8*)(W + (size_t)(n0 + r) * DIM + k0 + bcol);
            *(u16x8*)&lB[r][bcol] = v;
        }
        __syncthreads();

        bf16x8 af[4], bfr[4];
#pragma unroll
        for (int i = 0; i < 4; i++)
            af[i] = *(const bf16x8*)&lA[wr * 64 + i * 16 + (lane & 15)][(lane >> 4) * 8];
#pragma unroll
        for (int j = 0; j < 4; j++)
            bfr[j] = *(const bf16x8*)&lB[wc * 64 + j * 16 + (lane & 15)][(lane >> 4) * 8];
#pragma unroll
        for (int i = 0; i < 4; i++)
#pragma unroll
            for (int j = 0; j < 4; j++)
                acc[i][j] = __builtin_amdgcn_mfma_f32_16x16x32_bf16(af[i], bfr[j], acc[i][j], 0, 0, 0);
        __syncthreads();
    }

#pragma unroll
    for (int j = 0; j < 4; j++) {
        int n = n0 + wc * 64 + j * 16 + (lane & 15);
        float bv = bias[n];
#pragma unroll
        for (int i = 0; i < 4; i++) {
            int mbase = m0 + wr * 64 + i * 16 + (lane >> 4) * 4;
#pragma unroll
            for (int r = 0; r < 4; r++)
                out[(size_t)(mbase + r) * DIM + n] = f2bf(acc[i][j][r] + bv);
        }
    }
}

// ---------------- K2a: dots + softmax -> w_all[n][8] ----------------
__global__ __launch_bounds__(256) void dots_kernel(
    const float* __restrict__ s_att, const float* __restrict__ t_spatial,
    const unsigned short* __restrict__ t_next, const unsigned short* __restrict__ s_next,
    float* __restrict__ w_all)
{
    const int lane = threadIdx.x & 63;
    const int id = blockIdx.x;
    const int n = (id & 7) * 2048 + (id >> 3) * 4 + (threadIdx.x >> 6);
    const int c = lane * 8;
    const size_t rb = (size_t)n * DIM + c;
    const float scale = 0.04419417382415922f;  // 1/sqrt(512)

    f32x4 tn_a, tn_b, sn_a, sn_b;
    bf8_to_f32(*(const u16x8*)(t_next + rb), tn_a, tn_b);
    bf8_to_f32(*(const u16x8*)(s_next + rb), sn_a, sn_b);

    float dws[NTAU], dwt[NTAU];
#pragma unroll
    for (int k = 0; k < NTAU; k++) {
        const size_t kb = ((size_t)k * NTOK + n) * DIM + c;
        f32x4 a0 = NTLOAD4(s_att + kb);
        f32x4 a1 = NTLOAD4(s_att + kb + 4);
        f32x4 b0 = NTLOAD4(t_spatial + kb);
        f32x4 b1 = NTLOAD4(t_spatial + kb + 4);
        dws[k] = a0[0]*sn_a[0]+a0[1]*sn_a[1]+a0[2]*sn_a[2]+a0[3]*sn_a[3]
               + a1[0]*sn_b[0]+a1[1]*sn_b[1]+a1[2]*sn_b[2]+a1[3]*sn_b[3];
        dwt[k] = b0[0]*tn_a[0]+b0[1]*tn_a[1]+b0[2]*tn_a[2]+b0[3]*tn_a[3]
               + b1[0]*tn_b[0]+b1[1]*tn_b[1]+b1[2]*tn_b[2]+b1[3]*tn_b[3];
    }
#pragma unroll
    for (int k = 0; k < NTAU; k++) {
        float v = dws[k];
#pragma unroll
        for (int off = 32; off; off >>= 1) v += __shfl_xor(v, off);
        dws[k] = v * scale;
        float u = dwt[k];
#pragma unroll
        for (int off = 32; off; off >>= 1) u += __shfl_xor(u, off);
        dwt[k] = u * scale;
    }

    float ms = fmaxf(fmaxf(dws[0], dws[1]), fmaxf(dws[2], dws[3]));
    float mt = fmaxf(fmaxf(dwt[0], dwt[1]), fmaxf(dwt[2], dwt[3]));
    f32x4 wsv, wtv;
    float ssum = 0.f, tsum = 0.f;
#pragma unroll
    for (int k = 0; k < NTAU; k++) {
        wsv[k] = __expf(dws[k] - ms); ssum += wsv[k];
        wtv[k] = __expf(dwt[k] - mt); tsum += wtv[k];
    }
    float rs = 1.f / ssum, rt = 1.f / tsum;
#pragma unroll
    for (int k = 0; k < NTAU; k++) { wsv[k] *= rs; wtv[k] *= rt; }

    if (lane == 0) {
        *(f32x4*)(w_all + (size_t)n * 8)     = wsv;
        *(f32x4*)(w_all + (size_t)n * 8 + 4) = wtv;
    }
}

// ---------------- K2b: weighted trend + gates -> Tf, Sf (bf16) ----------------
__global__ __launch_bounds__(256) void fusion_kernel(
    const float* __restrict__ T_t, const float* __restrict__ S_t,
    const float* __restrict__ t_att, const float* __restrict__ s_spatial,
    const unsigned short* __restrict__ t_next, const unsigned short* __restrict__ s_next,
    const float* __restrict__ w_all,
    unsigned short* __restrict__ Tf, unsigned short* __restrict__ Sf)
{
    const int lane = threadIdx.x & 63;
    const int id = blockIdx.x;
    const int n = (id & 7) * 2048 + (id >> 3) * 4 + (threadIdx.x >> 6);
    const int c = lane * 8;
    const size_t rb = (size_t)n * DIM + c;

    f32x4 wsv = *(const f32x4*)(w_all + (size_t)n * 8);       // uniform (broadcast)
    f32x4 wtv = *(const f32x4*)(w_all + (size_t)n * 8 + 4);

    f32x4 Tta = {0,0,0,0}, Ttb = {0,0,0,0}, Sta = {0,0,0,0}, Stb = {0,0,0,0};
#pragma unroll
    for (int k = 0; k < NTAU; k++) {
        const size_t kb = ((size_t)k * NTOK + n) * DIM + c;
        f32x4 ta = NTLOAD4(t_att + kb);
        f32x4 tb = NTLOAD4(t_att + kb + 4);
        f32x4 sa = NTLOAD4(s_spatial + kb);
        f32x4 sb = NTLOAD4(s_spatial + kb + 4);
        float wk = wsv[k], vk = wtv[k];
#pragma unroll
        for (int e = 0; e < 4; e++) {
            Tta[e] += wk * ta[e]; Ttb[e] += wk * tb[e];
            Sta[e] += vk * sa[e]; Stb[e] += vk * sb[e];
        }
    }

    f32x4 tn_a, tn_b, sn_a, sn_b;
    bf8_to_f32(*(const u16x8*)(t_next + rb), tn_a, tn_b);
    bf8_to_f32(*(const u16x8*)(s_next + rb), sn_a, sn_b);
    f32x4 Ta = NTLOAD4(T_t + rb);
    f32x4 Tb = NTLOAD4(T_t + rb + 4);
    f32x4 Sa = NTLOAD4(S_t + rb);
    f32x4 Sb = NTLOAD4(S_t + rb + 4);

    u16x8 oT, oS;
#pragma unroll
    for (int e = 0; e < 4; e++) {
        float gt_a = 1.f / (1.f + __expf(-tn_a[e]));
        float gt_b = 1.f / (1.f + __expf(-tn_b[e]));
        float gs_a = 1.f / (1.f + __expf(-sn_a[e]));
        float gs_b = 1.f / (1.f + __expf(-sn_b[e]));
        oT[e]     = f2bf(Ta[e] * gt_a + (1.f - gt_a) * Tta[e]);
        oT[4 + e] = f2bf(Tb[e] * gt_b + (1.f - gt_b) * Ttb[e]);
        oS[e]     = f2bf(Sa[e] * gs_a + (1.f - gs_a) * Sta[e]);
        oS[4 + e] = f2bf(Sb[e] * gs_b + (1.f - gs_b) * Stb[e]);
    }
    *(u16x8*)(Tf + rb) = oT;
    *(u16x8*)(Sf + rb) = oS;
}

// ---------------- K3: final GEMM: A-only LDS (4x16KB), B coalesced L2->reg ------
// BM=128 BN=32, 512 thr = 8 waves {side, mh, jq}; per wave 4m x 1j x 3g, acc=48.
// B-frags from the PERMUTED W' (lane-contiguous 1KB loads, no LDS, no barrier dep).
// 4-slot depth-2 pipeline, counted vmcnt (5 VMEM ops/wave/iter: 2 gload + 3 B).
__global__ __launch_bounds__(512, 2) void gemm_final(
    const unsigned short* __restrict__ Tf, const unsigned short* __restrict__ Sf,
    const unsigned short* __restrict__ Wtp, const unsigned short* __restrict__ Wsp,
    const float* __restrict__ bt, const float* __restrict__ bs,
    float* __restrict__ out)
{
    __shared__ __align__(16) unsigned char smem[65536];   // 4 slots x 16 KB (A only)
    const int tid = threadIdx.x;
    const int id = blockIdx.x;                    // 0..2047
    const int xcd = id & 7;
    const int idx = id >> 3;                      // 0..255
    const int m0 = (xcd * 16 + (idx >> 4)) * 128;
    const int j0 = (idx & 15) * 32;
    const int lane = tid & 63;
    const int w = tid >> 6;                       // 0..7
    const int side = w >> 2;                      // 0 = T, 1 = S
    const int mh = (w >> 1) & 1;                  // m half (64 rows)
    const int jq = w & 1;                         // 16-col group

    f32x4 acc[3][4];
#pragma unroll
    for (int g = 0; g < 3; g++)
#pragma unroll
        for (int i = 0; i < 4; i++) acc[g][i] = (f32x4){0.f, 0.f, 0.f, 0.f};

    const int srow = lane >> 2;   // 0..15
    const int sg   = lane & 3;    // physical granule
    const int lg   = sg ^ ((srow >> 1) & 3);   // inverse-swizzled source granule

    // A slot: 16 chunks of 1KB: ch0..7 = Tf rows, ch8..15 = Sf rows. Wave w owns
    // chunks {w, w+8} (16 rows each).
    const unsigned short* gsrc0 = Tf + (size_t)(m0 + w * 16 + srow) * DIM + lg * 8;
    const unsigned short* gsrc1 = Sf + (size_t)(m0 + w * 16 + srow) * DIM + lg * 8;
    const int dst0 = w * 1024;
    const int dst1 = 8192 + w * 1024;

    // A-read byte offsets (K-invariant)
    const int pg = (lane >> 4) ^ (((lane & 15) >> 1) & 3);
    int axo[4];
#pragma unroll
    for (int i = 0; i < 4; i++)
        axo[i] = side * 8192 + (mh * 4 + i) * 1024 + (lane & 15) * 64 + pg * 16;

    // B pointers into permuted W': block (g,j16) = 8192 elems, k-step = 512 elems
    const unsigned short* Wp = side ? Wsp : Wtp;
    const int j16 = (idx & 15) * 2 + jq;
    const unsigned short* bp[3];
#pragma unroll
    for (int g = 0; g < 3; g++)
        bp[g] = Wp + ((size_t)(g * 32 + j16) * 16) * 512 + lane * 8;

    auto stage = [&](int slot) {
        unsigned char* d = smem + slot * 16384;
        gload16(gsrc0, d + dst0); gsrc0 += 32;
        gload16(gsrc1, d + dst1); gsrc1 += 32;
    };

    bf16x8 bcur[3], bnxt[3];
    stage(0);           // A(0)
    stage(1);           // A(1)
#pragma unroll
    for (int g = 0; g < 3; g++) { bcur[g] = *(const bf16x8*)bp[g]; bp[g] += 512; }

    for (int kt = 0; kt < 16; ++kt) {
        if (kt < 14) stage((kt + 2) & 3);                     // A(kt+2)
        if (kt < 15) {
#pragma unroll
            for (int g = 0; g < 3; g++) { bnxt[g] = *(const bf16x8*)bp[g]; bp[g] += 512; }
        }
        // drain own A(kt) gloads; keep newer stages + B prefetches in flight
        if (kt == 0)       asm volatile("s_waitcnt vmcnt(4)" ::: "memory");
        else if (kt < 14)  asm volatile("s_waitcnt vmcnt(10)" ::: "memory");
        else if (kt == 14) asm volatile("s_waitcnt vmcnt(8)" ::: "memory");
        else               asm volatile("s_waitcnt vmcnt(3)" ::: "memory");
        __builtin_amdgcn_s_barrier();
        __builtin_amdgcn_sched_barrier(0);

        const unsigned char* base = smem + (kt & 3) * 16384;
        bf16x8 ax[4];
#pragma unroll
        for (int i = 0; i < 4; i++) ax[i] = *(const bf16x8*)(base + axo[i]);
#pragma unroll
        for (int g = 0; g < 3; g++)
#pragma unroll
            for (int i = 0; i < 4; i++)
                acc[g][i] = __builtin_amdgcn_mfma_f32_16x16x32_bf16(ax[i], bcur[g], acc[g][i], 0, 0, 0);
        if (kt < 15) {
#pragma unroll
            for (int g = 0; g < 3; g++) bcur[g] = bnxt[g];
        }
    }
    __syncthreads();    // all reads done before epilogue reuses smem

    // ---- epilogue: exchange cross group via LDS (partner wave = w ^ 4) ----
    const int jcol = j0 + jq * 16 + (lane & 15);
    const float* bb = side ? bs : bt;
    const float bg   = bb[jcol];
    const float bown = side ? bb[1024 + jcol] : bb[512 + jcol];   // s_s / t_t
    const float bex  = side ? bb[512 + jcol]  : bb[1024 + jcol];  // s_t / t_s
    float* exf = (float*)smem;   // [8 waves][4 frags][64 lanes] f32x4 = 32 KB
#pragma unroll
    for (int i = 0; i < 4; i++) {
        f32x4 v = side ? acc[1][i] : acc[2][i];   // S exports s_t, T exports t_s
        v[0] += bex; v[1] += bex; v[2] += bex; v[3] += bex;
        *(f32x4*)(exf + ((w * 4 + i) * 64 + lane) * 4) = v;
    }
    __syncthreads();

    float* obase = out + (side ? (size_t)NTOK * DIM : 0);
#pragma unroll
    for (int i = 0; i < 4; i++) {
        f32x4 oth = *(const f32x4*)(exf + (((w ^ 4) * 4 + i) * 64 + lane) * 4);
        f32x4 own = side ? acc[2][i] : acc[1][i];
#pragma unroll
        for (int r = 0; r < 4; r++) {
            const float gate = 1.f / (1.f + __expf(-(acc[0][i][r] + bg)));
            obase[(size_t)(m0 + mh * 64 + i * 16 + (lane >> 4) * 4 + r) * DIM + jcol]
                = gate * (own[r] + bown) + (1.f - gate) * oth[r];
        }
    }
}

extern "C" void kernel_launch(void* const* d_in, const int* in_sizes, int n_in,
                              void* d_out, int out_size, void* d_ws, size_t ws_size,
                              hipStream_t stream) {
    const float* T_t       = (const float*)d_in[0];
    const float* S_t       = (const float*)d_in[1];
    const float* t_att     = (const float*)d_in[2];
    const float* s_att     = (const float*)d_in[3];
    const float* t_spatial = (const float*)d_in[4];
    const float* s_spatial = (const float*)d_in[5];
    const float* W_t  = (const float*)d_in[6];
    const float* b_t  = (const float*)d_in[7];
    const float* W_tn = (const float*)d_in[8];
    const float* b_tn = (const float*)d_in[9];
    const float* W_s  = (const float*)d_in[10];
    const float* b_s  = (const float*)d_in[11];
    const float* W_sn = (const float*)d_in[12];
    const float* b_sn = (const float*)d_in[13];
    float* out = (float*)d_out;

    char* ws = (char*)d_ws;
    unsigned short* t_next = (unsigned short*)(ws + 0);          // 16.8 MB
    unsigned short* s_next = (unsigned short*)(ws + 16777216);
    unsigned short* Tf     = (unsigned short*)(ws + 33554432);
    unsigned short* Sf     = (unsigned short*)(ws + 50331648);
    unsigned short* Wtn_b  = (unsigned short*)(ws + 67108864);
    unsigned short* Wsn_b  = (unsigned short*)(ws + 67633152);
    unsigned short* Wtp    = (unsigned short*)(ws + 68157440);   // permuted, 1.5 MB
    unsigned short* Wsp    = (unsigned short*)(ws + 69730304);
    float*          w_all  = (float*)(ws + 71303168);            // 512 KB

    convert2<<<512, 256, 0, stream>>>(W_tn, W_sn, Wtn_b, Wsn_b);
    convert_perm<<<768, 256, 0, stream>>>(W_t, W_s, Wtp, Wsp);

    gemm_next2<<<1024, 256, 0, stream>>>(T_t, S_t, Wtn_b, Wsn_b, b_tn, b_sn,
                                         t_next, s_next);

    dots_kernel<<<4096, 256, 0, stream>>>(s_att, t_spatial, t_next, s_next, w_all);

    fusion_kernel<<<4096, 256, 0, stream>>>(T_t, S_t, t_att, s_spatial,
                                            t_next, s_next, w_all, Tf, Sf);

    gemm_final<<<2048, 512, 0, stream>>>(Tf, Sf, Wtp, Wsp, b_t, b_s, out);
}

// Round 13
// 279.080 us; speedup vs baseline: 1.0621x; 1.0621x over previous
//
#include <hip/hip_runtime.h>

#define NTOK 16384
#define DIM 512
#define NTAU 4

typedef __attribute__((ext_vector_type(4))) float f32x4;
typedef __attribute__((ext_vector_type(8))) short bf16x8;   // 8 bf16 in 4 VGPRs
typedef __attribute__((ext_vector_type(4))) unsigned short u16x4;
typedef __attribute__((ext_vector_type(8))) unsigned short u16x8;
typedef unsigned int u32;

__device__ inline unsigned short f2bf(float f) {
    union { float f; unsigned int u; } v; v.f = f;
    unsigned int u = v.u + 0x7FFFu + ((v.u >> 16) & 1u);  // RNE
    return (unsigned short)(u >> 16);
}

__device__ inline void bf8_to_f32(u16x8 h, f32x4& a, f32x4& b) {
    union { unsigned int u; float f; } t;
#pragma unroll
    for (int e = 0; e < 4; e++) { t.u = ((unsigned int)h[e]) << 16; a[e] = t.f; }
#pragma unroll
    for (int e = 0; e < 4; e++) { t.u = ((unsigned int)h[4 + e]) << 16; b[e] = t.f; }
}

#define NTLOAD4(p) __builtin_nontemporal_load((const f32x4*)(p))

// async global -> LDS, 16 bytes per lane. LDS dest: wave-uniform base + lane*16.
__device__ __forceinline__ void gload16(const void* g, void* l) {
    __builtin_amdgcn_global_load_lds((const __attribute__((address_space(1))) u32*)g,
                                     (__attribute__((address_space(3))) u32*)l, 16, 0, 0);
}

// ---------------- K0: fp32 -> bf16 convert (all 4 weight mats, one launch) ----
__global__ void convert_all(const float* __restrict__ a, const float* __restrict__ b,
                            const float* __restrict__ c, const float* __restrict__ d,
                            unsigned short* __restrict__ oa, unsigned short* __restrict__ ob,
                            unsigned short* __restrict__ oc, unsigned short* __restrict__ od) {
    int i = blockIdx.x * 256 + threadIdx.x;   // 0..524287 (x4 units)
    const float* s; unsigned short* t; int off;
    if (i < 65536)       { s = a; t = oa; off = i; }
    else if (i < 131072) { s = b; t = ob; off = i - 65536; }
    else if (i < 327680) { s = c; t = oc; off = i - 131072; }
    else                 { s = d; t = od; off = i - 327680; }
    f32x4 v = ((const f32x4*)s)[off];
    u16x4 o;
    o[0] = f2bf(v[0]); o[1] = f2bf(v[1]); o[2] = f2bf(v[2]); o[3] = f2bf(v[3]);
    ((u16x4*)t)[off] = o;
}

// ---------------- K1: BOTH next-GEMMs in one launch (1024 blocks) ----------------
__global__ __launch_bounds__(256, 2) void gemm_next2(
    const float* __restrict__ T_t, const float* __restrict__ S_t,
    const unsigned short* __restrict__ Wtn, const unsigned short* __restrict__ Wsn,
    const float* __restrict__ btn, const float* __restrict__ bsn,
    unsigned short* __restrict__ t_next, unsigned short* __restrict__ s_next)
{
    __shared__ unsigned short lA[128][40];
    __shared__ unsigned short lB[128][40];
    const int tid = threadIdx.x;
    const int id = blockIdx.x;                    // 0..1023
    const int xcd = id & 7;
    const int rest = id >> 3;                     // 0..127
    const int mat = rest & 1;
    const int idx = rest >> 1;                    // 0..63
    const float* A = mat ? S_t : T_t;
    const unsigned short* W = mat ? Wsn : Wtn;
    const float* bias = mat ? bsn : btn;
    unsigned short* out = mat ? s_next : t_next;
    const int m0 = (xcd * 16 + (idx >> 2)) * 128;
    const int n0 = (idx & 3) * 128;
    const int lane = tid & 63;
    const int w = tid >> 6;
    const int wr = w >> 1, wc = w & 1;

    f32x4 acc[4][4];
#pragma unroll
    for (int i = 0; i < 4; i++)
#pragma unroll
        for (int j = 0; j < 4; j++) acc[i][j] = (f32x4){0.f, 0.f, 0.f, 0.f};

    const int arow = tid >> 3;
    const int acol = (tid & 7) * 4;
    const int brow = tid >> 2;
    const int bcol = (tid & 3) * 8;

    for (int k0 = 0; k0 < DIM; k0 += 32) {
#pragma unroll
        for (int i = 0; i < 4; i++) {
            int r = arow + 32 * i;
            f32x4 v = *(const f32x4*)(A + (size_t)(m0 + r) * DIM + k0 + acol);
            u16x4 o;
            o[0] = f2bf(v[0]); o[1] = f2bf(v[1]); o[2] = f2bf(v[2]); o[3] = f2bf(v[3]);
            *(u16x4*)&lA[r][acol] = o;
        }
#pragma unroll
        for (int i = 0; i < 2; i++) {
            int r = brow + 64 * i;
            u16x8 v = *(const u16x8*)(W + (size_t)(n0 + r) * DIM + k0 + bcol);
            *(u16x8*)&lB[r][bcol] = v;
        }
        __syncthreads();

        bf16x8 af[4], bfr[4];
#pragma unroll
        for (int i = 0; i < 4; i++)
            af[i] = *(const bf16x8*)&lA[wr * 64 + i * 16 + (lane & 15)][(lane >> 4) * 8];
#pragma unroll
        for (int j = 0; j < 4; j++)
            bfr[j] = *(const bf16x8*)&lB[wc * 64 + j * 16 + (lane & 15)][(lane >> 4) * 8];
#pragma unroll
        for (int i = 0; i < 4; i++)
#pragma unroll
            for (int j = 0; j < 4; j++)
                acc[i][j] = __builtin_amdgcn_mfma_f32_16x16x32_bf16(af[i], bfr[j], acc[i][j], 0, 0, 0);
        __syncthreads();
    }

#pragma unroll
    for (int j = 0; j < 4; j++) {
        int n = n0 + wc * 64 + j * 16 + (lane & 15);
        float bv = bias[n];
#pragma unroll
        for (int i = 0; i < 4; i++) {
            int mbase = m0 + wr * 64 + i * 16 + (lane >> 4) * 4;
#pragma unroll
            for (int r = 0; r < 4; r++)
                out[(size_t)(mbase + r) * DIM + n] = f2bf(acc[i][j][r] + bv);
        }
    }
}

// ---------------- K2a: dots + softmax -> w_all[n][8] ----------------
__global__ __launch_bounds__(256) void dots_kernel(
    const float* __restrict__ s_att, const float* __restrict__ t_spatial,
    const unsigned short* __restrict__ t_next, const unsigned short* __restrict__ s_next,
    float* __restrict__ w_all)
{
    const int lane = threadIdx.x & 63;
    const int id = blockIdx.x;
    const int n = (id & 7) * 2048 + (id >> 3) * 4 + (threadIdx.x >> 6);
    const int c = lane * 8;
    const size_t rb = (size_t)n * DIM + c;
    const float scale = 0.04419417382415922f;  // 1/sqrt(512)

    f32x4 tn_a, tn_b, sn_a, sn_b;
    bf8_to_f32(*(const u16x8*)(t_next + rb), tn_a, tn_b);
    bf8_to_f32(*(const u16x8*)(s_next + rb), sn_a, sn_b);

    float dws[NTAU], dwt[NTAU];
#pragma unroll
    for (int k = 0; k < NTAU; k++) {
        const size_t kb = ((size_t)k * NTOK + n) * DIM + c;
        f32x4 a0 = NTLOAD4(s_att + kb);
        f32x4 a1 = NTLOAD4(s_att + kb + 4);
        f32x4 b0 = NTLOAD4(t_spatial + kb);
        f32x4 b1 = NTLOAD4(t_spatial + kb + 4);
        dws[k] = a0[0]*sn_a[0]+a0[1]*sn_a[1]+a0[2]*sn_a[2]+a0[3]*sn_a[3]
               + a1[0]*sn_b[0]+a1[1]*sn_b[1]+a1[2]*sn_b[2]+a1[3]*sn_b[3];
        dwt[k] = b0[0]*tn_a[0]+b0[1]*tn_a[1]+b0[2]*tn_a[2]+b0[3]*tn_a[3]
               + b1[0]*tn_b[0]+b1[1]*tn_b[1]+b1[2]*tn_b[2]+b1[3]*tn_b[3];
    }
#pragma unroll
    for (int k = 0; k < NTAU; k++) {
        float v = dws[k];
#pragma unroll
        for (int off = 32; off; off >>= 1) v += __shfl_xor(v, off);
        dws[k] = v * scale;
        float u = dwt[k];
#pragma unroll
        for (int off = 32; off; off >>= 1) u += __shfl_xor(u, off);
        dwt[k] = u * scale;
    }

    float ms = fmaxf(fmaxf(dws[0], dws[1]), fmaxf(dws[2], dws[3]));
    float mt = fmaxf(fmaxf(dwt[0], dwt[1]), fmaxf(dwt[2], dwt[3]));
    f32x4 wsv, wtv;
    float ssum = 0.f, tsum = 0.f;
#pragma unroll
    for (int k = 0; k < NTAU; k++) {
        wsv[k] = __expf(dws[k] - ms); ssum += wsv[k];
        wtv[k] = __expf(dwt[k] - mt); tsum += wtv[k];
    }
    float rs = 1.f / ssum, rt = 1.f / tsum;
#pragma unroll
    for (int k = 0; k < NTAU; k++) { wsv[k] *= rs; wtv[k] *= rt; }

    if (lane == 0) {
        *(f32x4*)(w_all + (size_t)n * 8)     = wsv;
        *(f32x4*)(w_all + (size_t)n * 8 + 4) = wtv;
    }
}

// ---------------- K2b: weighted trend + gates -> Tf, Sf (bf16) ----------------
__global__ __launch_bounds__(256) void fusion_kernel(
    const float* __restrict__ T_t, const float* __restrict__ S_t,
    const float* __restrict__ t_att, const float* __restrict__ s_spatial,
    const unsigned short* __restrict__ t_next, const unsigned short* __restrict__ s_next,
    const float* __restrict__ w_all,
    unsigned short* __restrict__ Tf, unsigned short* __restrict__ Sf)
{
    const int lane = threadIdx.x & 63;
    const int id = blockIdx.x;
    const int n = (id & 7) * 2048 + (id >> 3) * 4 + (threadIdx.x >> 6);
    const int c = lane * 8;
    const size_t rb = (size_t)n * DIM + c;

    f32x4 wsv = *(const f32x4*)(w_all + (size_t)n * 8);       // uniform (broadcast)
    f32x4 wtv = *(const f32x4*)(w_all + (size_t)n * 8 + 4);

    f32x4 Tta = {0,0,0,0}, Ttb = {0,0,0,0}, Sta = {0,0,0,0}, Stb = {0,0,0,0};
#pragma unroll
    for (int k = 0; k < NTAU; k++) {
        const size_t kb = ((size_t)k * NTOK + n) * DIM + c;
        f32x4 ta = NTLOAD4(t_att + kb);
        f32x4 tb = NTLOAD4(t_att + kb + 4);
        f32x4 sa = NTLOAD4(s_spatial + kb);
        f32x4 sb = NTLOAD4(s_spatial + kb + 4);
        float wk = wsv[k], vk = wtv[k];
#pragma unroll
        for (int e = 0; e < 4; e++) {
            Tta[e] += wk * ta[e]; Ttb[e] += wk * tb[e];
            Sta[e] += vk * sa[e]; Stb[e] += vk * sb[e];
        }
    }

    f32x4 tn_a, tn_b, sn_a, sn_b;
    bf8_to_f32(*(const u16x8*)(t_next + rb), tn_a, tn_b);
    bf8_to_f32(*(const u16x8*)(s_next + rb), sn_a, sn_b);
    f32x4 Ta = NTLOAD4(T_t + rb);
    f32x4 Tb = NTLOAD4(T_t + rb + 4);
    f32x4 Sa = NTLOAD4(S_t + rb);
    f32x4 Sb = NTLOAD4(S_t + rb + 4);

    u16x8 oT, oS;
#pragma unroll
    for (int e = 0; e < 4; e++) {
        float gt_a = 1.f / (1.f + __expf(-tn_a[e]));
        float gt_b = 1.f / (1.f + __expf(-tn_b[e]));
        float gs_a = 1.f / (1.f + __expf(-sn_a[e]));
        float gs_b = 1.f / (1.f + __expf(-sn_b[e]));
        oT[e]     = f2bf(Ta[e] * gt_a + (1.f - gt_a) * Tta[e]);
        oT[4 + e] = f2bf(Tb[e] * gt_b + (1.f - gt_b) * Ttb[e]);
        oS[e]     = f2bf(Sa[e] * gs_a + (1.f - gs_a) * Sta[e]);
        oS[4 + e] = f2bf(Sb[e] * gs_b + (1.f - gs_b) * Stb[e]);
    }
    *(u16x8*)(Tf + rb) = oT;
    *(u16x8*)(Sf + rb) = oS;
}

// ---------------- K3: final GEMM, R9 layout + 2-phase counted-vmcnt ----------
// BM=128 BN=32, 512 thr = 8 waves {side, mh, jq}; per wave 4m x 1j x 3g, acc=48.
// LDS: 2 slots x 28 KB (A: 256 rows x32, W: 192 rows x32) = 56 KB -> 2 blocks/CU.
// Per iter: stage(kt+1) -> vmcnt(keep newest stage: 4 for w<4, 3 else) ->
// s_barrier -> ds_read + MFMA -> lgkmcnt(0) + s_barrier (protects slot reuse).
__global__ __launch_bounds__(512, 2) void gemm_final(
    const unsigned short* __restrict__ Tf, const unsigned short* __restrict__ Sf,
    const unsigned short* __restrict__ Wt, const unsigned short* __restrict__ Ws,
    const float* __restrict__ bt, const float* __restrict__ bs,
    float* __restrict__ out)
{
    __shared__ __align__(16) unsigned char smem[57344];   // 2 x 28672 B slots
    const int tid = threadIdx.x;
    const int id = blockIdx.x;                    // 0..2047
    const int xcd = id & 7;
    const int idx = id >> 3;                      // 0..255
    const int m0 = (xcd * 16 + (idx >> 4)) * 128;
    const int j0 = (idx & 15) * 32;
    const int lane = tid & 63;
    const int w = tid >> 6;                       // 0..7
    const int side = w >> 2;                      // 0 = T, 1 = S
    const int mh = (w >> 1) & 1;                  // m half (64 rows)
    const int jq = w & 1;                         // 16-col group
    const bool w4 = (w < 4);

    f32x4 acc[3][4];
#pragma unroll
    for (int g = 0; g < 3; g++)
#pragma unroll
        for (int i = 0; i < 4; i++) acc[g][i] = (f32x4){0.f, 0.f, 0.f, 0.f};

    const int srow = lane >> 2;   // 0..15
    const int sg   = lane & 3;    // physical granule
    const int lg   = sg ^ ((srow >> 1) & 3);   // inverse-swizzled source granule

    // 28 chunks of 16 rows x 32 cols (1KB): ch0..7 Tf, ch8..15 Sf, ch16..27 W.
    // Wave w owns chunks {w, 8+w, 16+w, 24+w (if w<4)}.
    const unsigned short* gsrc[4];
    int dsto[4];
#pragma unroll
    for (int i = 0; i < 4; i++) {
        const int ch = i * 8 + w;
        dsto[i] = ch * 1024;
        const unsigned short* p = Tf;
        if (ch < 8) {
            p = Tf + (size_t)(m0 + ch * 16 + srow) * DIM + lg * 8;
        } else if (ch < 16) {
            p = Sf + (size_t)(m0 + (ch - 8) * 16 + srow) * DIM + lg * 8;
        } else if (ch < 28) {
            const int r = (ch - 16) * 16 + srow;          // 0..191
            const int g = r >> 5;                         // 0..5
            const unsigned short* src = (g < 3) ? Wt : Ws;
            const int wrow = (g < 3 ? g : g - 3) * DIM + j0 + (r & 31);
            p = src + (size_t)wrow * DIM + lg * 8;
        }
        gsrc[i] = p;
    }

    // Reader byte offsets (K-invariant). pg depends only on lane.
    const int pg = (lane >> 4) ^ (((lane & 15) >> 1) & 3);
    int axo[4], bwo[3];
#pragma unroll
    for (int i = 0; i < 4; i++) {
        const int row = mh * 64 + i * 16 + (lane & 15);
        axo[i] = (side * 128 + row) * 64 + pg * 16;
    }
#pragma unroll
    for (int g = 0; g < 3; g++) {
        const int r = (side * 3 + g) * 32 + jq * 16 + (lane & 15);
        bwo[g] = 16384 + r * 64 + pg * 16;
    }

    auto stage = [&](int slot) {
        unsigned char* d = smem + slot * 28672;
#pragma unroll
        for (int i = 0; i < 4; i++) {
            if (i < 3 || w4) {
                gload16(gsrc[i], d + dsto[i]);
                gsrc[i] += 32;
            }
        }
    };

    stage(0);
    for (int kt = 0; kt < 16; ++kt) {
        if (kt < 15) {
            stage((kt + 1) & 1);
            // drain stage(kt), keep stage(kt+1) in flight
            if (w4) asm volatile("s_waitcnt vmcnt(4)" ::: "memory");
            else    asm volatile("s_waitcnt vmcnt(3)" ::: "memory");
        } else {
            asm volatile("s_waitcnt vmcnt(0)" ::: "memory");
        }
        __builtin_amdgcn_s_barrier();
        __builtin_amdgcn_sched_barrier(0);

        const unsigned char* base = smem + (kt & 1) * 28672;
        bf16x8 ax[4], bw[3];
#pragma unroll
        for (int i = 0; i < 4; i++) ax[i] = *(const bf16x8*)(base + axo[i]);
#pragma unroll
        for (int g = 0; g < 3; g++) bw[g] = *(const bf16x8*)(base + bwo[g]);
#pragma unroll
        for (int g = 0; g < 3; g++)
#pragma unroll
            for (int i = 0; i < 4; i++)
                acc[g][i] = __builtin_amdgcn_mfma_f32_16x16x32_bf16(ax[i], bw[g], acc[g][i], 0, 0, 0);

        // all my ds_reads of this slot complete, then sync -> safe to restage
        asm volatile("s_waitcnt lgkmcnt(0)" ::: "memory");
        __builtin_amdgcn_sched_barrier(0);
        __builtin_amdgcn_s_barrier();
    }
    __syncthreads();    // full drain before epilogue reuses smem

    // ---- epilogue: exchange cross group via LDS (partner wave = w ^ 4) ----
    const int jcol = j0 + jq * 16 + (lane & 15);
    const float* bb = side ? bs : bt;
    const float bg   = bb[jcol];
    const float bown = side ? bb[1024 + jcol] : bb[512 + jcol];   // s_s / t_t
    const float bex  = side ? bb[512 + jcol]  : bb[1024 + jcol];  // s_t / t_s
    float* exf = (float*)smem;   // [8 waves][4 frags][64 lanes] f32x4 = 32 KB
#pragma unroll
    for (int i = 0; i < 4; i++) {
        f32x4 v = side ? acc[1][i] : acc[2][i];   // S exports s_t, T exports t_s
        v[0] += bex; v[1] += bex; v[2] += bex; v[3] += bex;
        *(f32x4*)(exf + ((w * 4 + i) * 64 + lane) * 4) = v;
    }
    __syncthreads();

    float* obase = out + (side ? (size_t)NTOK * DIM : 0);
#pragma unroll
    for (int i = 0; i < 4; i++) {
        f32x4 oth = *(const f32x4*)(exf + (((w ^ 4) * 4 + i) * 64 + lane) * 4);
        f32x4 own = side ? acc[2][i] : acc[1][i];
#pragma unroll
        for (int r = 0; r < 4; r++) {
            const float gate = 1.f / (1.f + __expf(-(acc[0][i][r] + bg)));
            obase[(size_t)(m0 + mh * 64 + i * 16 + (lane >> 4) * 4 + r) * DIM + jcol]
                = gate * (own[r] + bown) + (1.f - gate) * oth[r];
        }
    }
}

extern "C" void kernel_launch(void* const* d_in, const int* in_sizes, int n_in,
                              void* d_out, int out_size, void* d_ws, size_t ws_size,
                              hipStream_t stream) {
    const float* T_t       = (const float*)d_in[0];
    const float* S_t       = (const float*)d_in[1];
    const float* t_att     = (const float*)d_in[2];
    const float* s_att     = (const float*)d_in[3];
    const float* t_spatial = (const float*)d_in[4];
    const float* s_spatial = (const float*)d_in[5];
    const float* W_t  = (const float*)d_in[6];
    const float* b_t  = (const float*)d_in[7];
    const float* W_tn = (const float*)d_in[8];
    const float* b_tn = (const float*)d_in[9];
    const float* W_s  = (const float*)d_in[10];
    const float* b_s  = (const float*)d_in[11];
    const float* W_sn = (const float*)d_in[12];
    const float* b_sn = (const float*)d_in[13];
    float* out = (float*)d_out;

    char* ws = (char*)d_ws;
    unsigned short* t_next = (unsigned short*)(ws + 0);          // 16.8 MB
    unsigned short* s_next = (unsigned short*)(ws + 16777216);
    unsigned short* Tf     = (unsigned short*)(ws + 33554432);
    unsigned short* Sf     = (unsigned short*)(ws + 50331648);
    unsigned short* Wtn_b  = (unsigned short*)(ws + 67108864);
    unsigned short* Wsn_b  = (unsigned short*)(ws + 67633152);
    unsigned short* Wt_b   = (unsigned short*)(ws + 68157440);
    unsigned short* Ws_b   = (unsigned short*)(ws + 69730304);
    float*          w_all  = (float*)(ws + 71303168);            // 512 KB

    convert_all<<<2048, 256, 0, stream>>>(W_tn, W_sn, W_t, W_s,
                                          Wtn_b, Wsn_b, Wt_b, Ws_b);

    gemm_next2<<<1024, 256, 0, stream>>>(T_t, S_t, Wtn_b, Wsn_b, b_tn, b_sn,
                                         t_next, s_next);

    dots_kernel<<<4096, 256, 0, stream>>>(s_att, t_spatial, t_next, s_next, w_all);

    fusion_kernel<<<4096, 256, 0, stream>>>(T_t, S_t, t_att, s_spatial,
                                            t_next, s_next, w_all, Tf, Sf);

    gemm_final<<<2048, 512, 0, stream>>>(Tf, Sf, Wt_b, Ws_b, b_t, b_s, out);
}

// Round 15
// 276.617 us; speedup vs baseline: 1.0716x; 1.0089x over previous
//
#include <hip/hip_runtime.h>

#define NTOK 16384
#define DIM 512
#define NTAU 4

typedef __attribute__((ext_vector_type(4))) float f32x4;
typedef __attribute__((ext_vector_type(8))) short bf16x8;   // 8 bf16 in 4 VGPRs
typedef __attribute__((ext_vector_type(4))) unsigned short u16x4;
typedef __attribute__((ext_vector_type(8))) unsigned short u16x8;
typedef unsigned int u32;

__device__ inline unsigned short f2bf(float f) {
    union { float f; unsigned int u; } v; v.f = f;
    unsigned int u = v.u + 0x7FFFu + ((v.u >> 16) & 1u);  // RNE
    return (unsigned short)(u >> 16);
}

__device__ inline void bf8_to_f32(u16x8 h, f32x4& a, f32x4& b) {
    union { unsigned int u; float f; } t;
#pragma unroll
    for (int e = 0; e < 4; e++) { t.u = ((unsigned int)h[e]) << 16; a[e] = t.f; }
#pragma unroll
    for (int e = 0; e < 4; e++) { t.u = ((unsigned int)h[4 + e]) << 16; b[e] = t.f; }
}

#define NTLOAD4(p) __builtin_nontemporal_load((const f32x4*)(p))

// async global -> LDS, 16 bytes per lane. LDS dest: wave-uniform base + lane*16.
__device__ __forceinline__ void gload16(const void* g, void* l) {
    __builtin_amdgcn_global_load_lds((const __attribute__((address_space(1))) u32*)g,
                                     (__attribute__((address_space(3))) u32*)l, 16, 0, 0);
}

// ---------------- K0: fp32 -> bf16 convert (all 4 weight mats, one launch) ----
__global__ void convert_all(const float* __restrict__ a, const float* __restrict__ b,
                            const float* __restrict__ c, const float* __restrict__ d,
                            unsigned short* __restrict__ oa, unsigned short* __restrict__ ob,
                            unsigned short* __restrict__ oc, unsigned short* __restrict__ od) {
    int i = blockIdx.x * 256 + threadIdx.x;   // 0..524287 (x4 units)
    const float* s; unsigned short* t; int off;
    if (i < 65536)       { s = a; t = oa; off = i; }
    else if (i < 131072) { s = b; t = ob; off = i - 65536; }
    else if (i < 327680) { s = c; t = oc; off = i - 131072; }
    else                 { s = d; t = od; off = i - 327680; }
    f32x4 v = ((const f32x4*)s)[off];
    u16x4 o;
    o[0] = f2bf(v[0]); o[1] = f2bf(v[1]); o[2] = f2bf(v[2]); o[3] = f2bf(v[3]);
    ((u16x4*)t)[off] = o;
}

// ---------------- K1: BOTH next-GEMMs in one launch (1024 blocks) ----------------
__global__ __launch_bounds__(256, 2) void gemm_next2(
    const float* __restrict__ T_t, const float* __restrict__ S_t,
    const unsigned short* __restrict__ Wtn, const unsigned short* __restrict__ Wsn,
    const float* __restrict__ btn, const float* __restrict__ bsn,
    unsigned short* __restrict__ t_next, unsigned short* __restrict__ s_next)
{
    __shared__ unsigned short lA[128][40];
    __shared__ unsigned short lB[128][40];
    const int tid = threadIdx.x;
    const int id = blockIdx.x;                    // 0..1023
    const int xcd = id & 7;
    const int rest = id >> 3;                     // 0..127
    const int mat = rest & 1;
    const int idx = rest >> 1;                    // 0..63
    const float* A = mat ? S_t : T_t;
    const unsigned short* W = mat ? Wsn : Wtn;
    const float* bias = mat ? bsn : btn;
    unsigned short* out = mat ? s_next : t_next;
    const int m0 = (xcd * 16 + (idx >> 2)) * 128;
    const int n0 = (idx & 3) * 128;
    const int lane = tid & 63;
    const int w = tid >> 6;
    const int wr = w >> 1, wc = w & 1;

    f32x4 acc[4][4];
#pragma unroll
    for (int i = 0; i < 4; i++)
#pragma unroll
        for (int j = 0; j < 4; j++) acc[i][j] = (f32x4){0.f, 0.f, 0.f, 0.f};

    const int arow = tid >> 3;
    const int acol = (tid & 7) * 4;
    const int brow = tid >> 2;
    const int bcol = (tid & 3) * 8;

    for (int k0 = 0; k0 < DIM; k0 += 32) {
#pragma unroll
        for (int i = 0; i < 4; i++) {
            int r = arow + 32 * i;
            f32x4 v = *(const f32x4*)(A + (size_t)(m0 + r) * DIM + k0 + acol);
            u16x4 o;
            o[0] = f2bf(v[0]); o[1] = f2bf(v[1]); o[2] = f2bf(v[2]); o[3] = f2bf(v[3]);
            *(u16x4*)&lA[r][acol] = o;
        }
#pragma unroll
        for (int i = 0; i < 2; i++) {
            int r = brow + 64 * i;
            u16x8 v = *(const u16x8*)(W + (size_t)(n0 + r) * DIM + k0 + bcol);
            *(u16x8*)&lB[r][bcol] = v;
        }
        __syncthreads();

        bf16x8 af[4], bfr[4];
#pragma unroll
        for (int i = 0; i < 4; i++)
            af[i] = *(const bf16x8*)&lA[wr * 64 + i * 16 + (lane & 15)][(lane >> 4) * 8];
#pragma unroll
        for (int j = 0; j < 4; j++)
            bfr[j] = *(const bf16x8*)&lB[wc * 64 + j * 16 + (lane & 15)][(lane >> 4) * 8];
#pragma unroll
        for (int i = 0; i < 4; i++)
#pragma unroll
            for (int j = 0; j < 4; j++)
                acc[i][j] = __builtin_amdgcn_mfma_f32_16x16x32_bf16(af[i], bfr[j], acc[i][j], 0, 0, 0);
        __syncthreads();
    }

#pragma unroll
    for (int j = 0; j < 4; j++) {
        int n = n0 + wc * 64 + j * 16 + (lane & 15);
        float bv = bias[n];
#pragma unroll
        for (int i = 0; i < 4; i++) {
            int mbase = m0 + wr * 64 + i * 16 + (lane >> 4) * 4;
#pragma unroll
            for (int r = 0; r < 4; r++)
                out[(size_t)(mbase + r) * DIM + n] = f2bf(acc[i][j][r] + bv);
        }
    }
}

// ---------------- K2a: dots + softmax -> w_all[n][8] ----------------
__global__ __launch_bounds__(256) void dots_kernel(
    const float* __restrict__ s_att, const float* __restrict__ t_spatial,
    const unsigned short* __restrict__ t_next, const unsigned short* __restrict__ s_next,
    float* __restrict__ w_all)
{
    const int lane = threadIdx.x & 63;
    const int id = blockIdx.x;
    const int n = (id & 7) * 2048 + (id >> 3) * 4 + (threadIdx.x >> 6);
    const int c = lane * 8;
    const size_t rb = (size_t)n * DIM + c;
    const float scale = 0.04419417382415922f;  // 1/sqrt(512)

    f32x4 tn_a, tn_b, sn_a, sn_b;
    bf8_to_f32(*(const u16x8*)(t_next + rb), tn_a, tn_b);
    bf8_to_f32(*(const u16x8*)(s_next + rb), sn_a, sn_b);

    float dws[NTAU], dwt[NTAU];
#pragma unroll
    for (int k = 0; k < NTAU; k++) {
        const size_t kb = ((size_t)k * NTOK + n) * DIM + c;
        f32x4 a0 = NTLOAD4(s_att + kb);
        f32x4 a1 = NTLOAD4(s_att + kb + 4);
        f32x4 b0 = NTLOAD4(t_spatial + kb);
        f32x4 b1 = NTLOAD4(t_spatial + kb + 4);
        dws[k] = a0[0]*sn_a[0]+a0[1]*sn_a[1]+a0[2]*sn_a[2]+a0[3]*sn_a[3]
               + a1[0]*sn_b[0]+a1[1]*sn_b[1]+a1[2]*sn_b[2]+a1[3]*sn_b[3];
        dwt[k] = b0[0]*tn_a[0]+b0[1]*tn_a[1]+b0[2]*tn_a[2]+b0[3]*tn_a[3]
               + b1[0]*tn_b[0]+b1[1]*tn_b[1]+b1[2]*tn_b[2]+b1[3]*tn_b[3];
    }
#pragma unroll
    for (int k = 0; k < NTAU; k++) {
        float v = dws[k];
#pragma unroll
        for (int off = 32; off; off >>= 1) v += __shfl_xor(v, off);
        dws[k] = v * scale;
        float u = dwt[k];
#pragma unroll
        for (int off = 32; off; off >>= 1) u += __shfl_xor(u, off);
        dwt[k] = u * scale;
    }

    float ms = fmaxf(fmaxf(dws[0], dws[1]), fmaxf(dws[2], dws[3]));
    float mt = fmaxf(fmaxf(dwt[0], dwt[1]), fmaxf(dwt[2], dwt[3]));
    f32x4 wsv, wtv;
    float ssum = 0.f, tsum = 0.f;
#pragma unroll
    for (int k = 0; k < NTAU; k++) {
        wsv[k] = __expf(dws[k] - ms); ssum += wsv[k];
        wtv[k] = __expf(dwt[k] - mt); tsum += wtv[k];
    }
    float rs = 1.f / ssum, rt = 1.f / tsum;
#pragma unroll
    for (int k = 0; k < NTAU; k++) { wsv[k] *= rs; wtv[k] *= rt; }

    if (lane == 0) {
        *(f32x4*)(w_all + (size_t)n * 8)     = wsv;
        *(f32x4*)(w_all + (size_t)n * 8 + 4) = wtv;
    }
}

// ---------------- K2b: weighted trend + gates -> Tf, Sf (bf16) ----------------
__global__ __launch_bounds__(256) void fusion_kernel(
    const float* __restrict__ T_t, const float* __restrict__ S_t,
    const float* __restrict__ t_att, const float* __restrict__ s_spatial,
    const unsigned short* __restrict__ t_next, const unsigned short* __restrict__ s_next,
    const float* __restrict__ w_all,
    unsigned short* __restrict__ Tf, unsigned short* __restrict__ Sf)
{
    const int lane = threadIdx.x & 63;
    const int id = blockIdx.x;
    const int n = (id & 7) * 2048 + (id >> 3) * 4 + (threadIdx.x >> 6);
    const int c = lane * 8;
    const size_t rb = (size_t)n * DIM + c;

    f32x4 wsv = *(const f32x4*)(w_all + (size_t)n * 8);       // uniform (broadcast)
    f32x4 wtv = *(const f32x4*)(w_all + (size_t)n * 8 + 4);

    f32x4 Tta = {0,0,0,0}, Ttb = {0,0,0,0}, Sta = {0,0,0,0}, Stb = {0,0,0,0};
#pragma unroll
    for (int k = 0; k < NTAU; k++) {
        const size_t kb = ((size_t)k * NTOK + n) * DIM + c;
        f32x4 ta = NTLOAD4(t_att + kb);
        f32x4 tb = NTLOAD4(t_att + kb + 4);
        f32x4 sa = NTLOAD4(s_spatial + kb);
        f32x4 sb = NTLOAD4(s_spatial + kb + 4);
        float wk = wsv[k], vk = wtv[k];
#pragma unroll
        for (int e = 0; e < 4; e++) {
            Tta[e] += wk * ta[e]; Ttb[e] += wk * tb[e];
            Sta[e] += vk * sa[e]; Stb[e] += vk * sb[e];
        }
    }

    f32x4 tn_a, tn_b, sn_a, sn_b;
    bf8_to_f32(*(const u16x8*)(t_next + rb), tn_a, tn_b);
    bf8_to_f32(*(const u16x8*)(s_next + rb), sn_a, sn_b);
    f32x4 Ta = NTLOAD4(T_t + rb);
    f32x4 Tb = NTLOAD4(T_t + rb + 4);
    f32x4 Sa = NTLOAD4(S_t + rb);
    f32x4 Sb = NTLOAD4(S_t + rb + 4);

    u16x8 oT, oS;
#pragma unroll
    for (int e = 0; e < 4; e++) {
        float gt_a = 1.f / (1.f + __expf(-tn_a[e]));
        float gt_b = 1.f / (1.f + __expf(-tn_b[e]));
        float gs_a = 1.f / (1.f + __expf(-sn_a[e]));
        float gs_b = 1.f / (1.f + __expf(-sn_b[e]));
        oT[e]     = f2bf(Ta[e] * gt_a + (1.f - gt_a) * Tta[e]);
        oT[4 + e] = f2bf(Tb[e] * gt_b + (1.f - gt_b) * Ttb[e]);
        oS[e]     = f2bf(Sa[e] * gs_a + (1.f - gs_a) * Sta[e]);
        oS[4 + e] = f2bf(Sb[e] * gs_b + (1.f - gs_b) * Stb[e]);
    }
    *(u16x8*)(Tf + rb) = oT;
    *(u16x8*)(Sf + rb) = oS;
}

// ---------------- K3: final GEMM, split-depth prefetch (ORDER-FIXED) ----------
// R13 layout (BM=128 BN=32, 8 waves {side,mh,jq}, acc=48) with A/W pools split:
// A (HBM-resident Tf/Sf): 3 slots x 16 KB, prefetch distance 2.
// W (L2-resident):        2 slots x 12 KB, prefetch distance 1.
// CRITICAL: stageW(kt+1) is issued BEFORE stageA(kt+2) so the per-wave VMEM
// FIFO is A(kt), W(kt), A(kt+1), W(kt+1), A(kt+2) — steady vmcnt(6)/(5) then
// drains exactly A(kt)+W(kt). (R14 had the order flipped -> W(kt) unforced.)
__global__ __launch_bounds__(512, 2) void gemm_final(
    const unsigned short* __restrict__ Tf, const unsigned short* __restrict__ Sf,
    const unsigned short* __restrict__ Wt, const unsigned short* __restrict__ Ws,
    const float* __restrict__ bt, const float* __restrict__ bs,
    float* __restrict__ out)
{
    __shared__ __align__(16) unsigned char smem[73728];   // A: 3x16384, W: 2x12288
    const int tid = threadIdx.x;
    const int id = blockIdx.x;                    // 0..2047
    const int xcd = id & 7;
    const int idx = id >> 3;                      // 0..255
    const int m0 = (xcd * 16 + (idx >> 4)) * 128;
    const int j0 = (idx & 15) * 32;
    const int lane = tid & 63;
    const int w = tid >> 6;                       // 0..7
    const int side = w >> 2;                      // 0 = T, 1 = S
    const int mh = (w >> 1) & 1;                  // m half (64 rows)
    const int jq = w & 1;                         // 16-col group
    const bool w4 = (w < 4);

    f32x4 acc[3][4];
#pragma unroll
    for (int g = 0; g < 3; g++)
#pragma unroll
        for (int i = 0; i < 4; i++) acc[g][i] = (f32x4){0.f, 0.f, 0.f, 0.f};

    const int srow = lane >> 2;   // 0..15
    const int sg   = lane & 3;    // physical granule
    const int lg   = sg ^ ((srow >> 1) & 3);   // inverse-swizzled source granule

    // A staging: 16 chunks of 1KB per slot: ch0..7 Tf, ch8..15 Sf. Wave w owns
    // chunks {w, 8+w}.
    const unsigned short* gsA0 = Tf + (size_t)(m0 + w * 16 + srow) * DIM + lg * 8;
    const unsigned short* gsA1 = Sf + (size_t)(m0 + w * 16 + srow) * DIM + lg * 8;
    const int dA0 = w * 1024;
    const int dA1 = 8192 + w * 1024;

    // W staging: 12 chunks of 1KB per slot (192 rows). w<4 own ch {2w,2w+1};
    // w>=4 own ch {w+4}.
    const unsigned short* gsW0;
    const unsigned short* gsW1 = nullptr;
    int dW0, dW1 = 0;
    {
        auto wsrc = [&](int ch) {
            const int r = ch * 16 + srow;                 // 0..191
            const int g = r >> 5;                         // 0..5
            const unsigned short* src = (g < 3) ? Wt : Ws;
            const int wrow = (g < 3 ? g : g - 3) * DIM + j0 + (r & 31);
            return src + (size_t)wrow * DIM + lg * 8;
        };
        if (w4) {
            gsW0 = wsrc(2 * w);     dW0 = (2 * w) * 1024;
            gsW1 = wsrc(2 * w + 1); dW1 = (2 * w + 1) * 1024;
        } else {
            gsW0 = wsrc(w + 4);     dW0 = (w + 4) * 1024;
        }
    }

    // Reader byte offsets (K-invariant). pg depends only on lane.
    const int pg = (lane >> 4) ^ (((lane & 15) >> 1) & 3);
    int axo[4], bwo[3];
#pragma unroll
    for (int i = 0; i < 4; i++) {
        const int row = mh * 64 + i * 16 + (lane & 15);
        axo[i] = (side * 128 + row) * 64 + pg * 16;
    }
#pragma unroll
    for (int g = 0; g < 3; g++) {
        const int r = (side * 3 + g) * 32 + jq * 16 + (lane & 15);
        bwo[g] = r * 64 + pg * 16;
    }

    auto stageA = [&](int slot) {
        unsigned char* d = smem + slot * 16384;
        gload16(gsA0, d + dA0); gsA0 += 32;
        gload16(gsA1, d + dA1); gsA1 += 32;
    };
    auto stageW = [&](int slot) {
        unsigned char* d = smem + 49152 + slot * 12288;
        gload16(gsW0, d + dW0); gsW0 += 32;
        if (w4) { gload16(gsW1, d + dW1); gsW1 += 32; }
    };

    stageA(0); stageW(0);
    stageA(1);

    int sa = 0;      // slot of A(kt)
    int sa2 = 2;     // slot for A(kt+2)
    for (int kt = 0; kt < 16; ++kt) {
        // W FIRST, then A — keeps the VMEM FIFO in (W(kt+1), A(kt+2)) order so
        // the counted drain below releases exactly A(kt)+W(kt).
        if (kt + 1 < 16) stageW((kt + 1) & 1);
        if (kt + 2 < 16) stageA(sa2);

        if (kt < 14) {
            if (w4) asm volatile("s_waitcnt vmcnt(6)" ::: "memory");
            else    asm volatile("s_waitcnt vmcnt(5)" ::: "memory");
        } else if (kt == 14) {
            if (w4) asm volatile("s_waitcnt vmcnt(4)" ::: "memory");
            else    asm volatile("s_waitcnt vmcnt(3)" ::: "memory");
        } else {
            asm volatile("s_waitcnt vmcnt(0)" ::: "memory");
        }
        __builtin_amdgcn_s_barrier();
        __builtin_amdgcn_sched_barrier(0);

        const unsigned char* abase = smem + sa * 16384;
        const unsigned char* wbase = smem + 49152 + (kt & 1) * 12288;
        bf16x8 ax[4], bw[3];
#pragma unroll
        for (int i = 0; i < 4; i++) ax[i] = *(const bf16x8*)(abase + axo[i]);
#pragma unroll
        for (int g = 0; g < 3; g++) bw[g] = *(const bf16x8*)(wbase + bwo[g]);
#pragma unroll
        for (int g = 0; g < 3; g++)
#pragma unroll
            for (int i = 0; i < 4; i++)
                acc[g][i] = __builtin_amdgcn_mfma_f32_16x16x32_bf16(ax[i], bw[g], acc[g][i], 0, 0, 0);

        // all my ds_reads of these slots complete, then sync -> safe to restage
        asm volatile("s_waitcnt lgkmcnt(0)" ::: "memory");
        __builtin_amdgcn_sched_barrier(0);
        __builtin_amdgcn_s_barrier();

        sa = (sa == 2) ? 0 : sa + 1;
        sa2 = (sa2 == 2) ? 0 : sa2 + 1;
    }
    __syncthreads();    // full drain before epilogue reuses smem

    // ---- epilogue: exchange cross group via LDS (partner wave = w ^ 4) ----
    const int jcol = j0 + jq * 16 + (lane & 15);
    const float* bb = side ? bs : bt;
    const float bg   = bb[jcol];
    const float bown = side ? bb[1024 + jcol] : bb[512 + jcol];   // s_s / t_t
    const float bex  = side ? bb[512 + jcol]  : bb[1024 + jcol];  // s_t / t_s
    float* exf = (float*)smem;   // [8 waves][4 frags][64 lanes] f32x4 = 32 KB
#pragma unroll
    for (int i = 0; i < 4; i++) {
        f32x4 v = side ? acc[1][i] : acc[2][i];   // S exports s_t, T exports t_s
        v[0] += bex; v[1] += bex; v[2] += bex; v[3] += bex;
        *(f32x4*)(exf + ((w * 4 + i) * 64 + lane) * 4) = v;
    }
    __syncthreads();

    float* obase = out + (side ? (size_t)NTOK * DIM : 0);
#pragma unroll
    for (int i = 0; i < 4; i++) {
        f32x4 oth = *(const f32x4*)(exf + (((w ^ 4) * 4 + i) * 64 + lane) * 4);
        f32x4 own = side ? acc[2][i] : acc[1][i];
#pragma unroll
        for (int r = 0; r < 4; r++) {
            const float gate = 1.f / (1.f + __expf(-(acc[0][i][r] + bg)));
            obase[(size_t)(m0 + mh * 64 + i * 16 + (lane >> 4) * 4 + r) * DIM + jcol]
                = gate * (own[r] + bown) + (1.f - gate) * oth[r];
        }
    }
}

extern "C" void kernel_launch(void* const* d_in, const int* in_sizes, int n_in,
                              void* d_out, int out_size, void* d_ws, size_t ws_size,
                              hipStream_t stream) {
    const float* T_t       = (const float*)d_in[0];
    const float* S_t       = (const float*)d_in[1];
    const float* t_att     = (const float*)d_in[2];
    const float* s_att     = (const float*)d_in[3];
    const float* t_spatial = (const float*)d_in[4];
    const float* s_spatial = (const float*)d_in[5];
    const float* W_t  = (const float*)d_in[6];
    const float* b_t  = (const float*)d_in[7];
    const float* W_tn = (const float*)d_in[8];
    const float* b_tn = (const float*)d_in[9];
    const float* W_s  = (const float*)d_in[10];
    const float* b_s  = (const float*)d_in[11];
    const float* W_sn = (const float*)d_in[12];
    const float* b_sn = (const float*)d_in[13];
    float* out = (float*)d_out;

    char* ws = (char*)d_ws;
    unsigned short* t_next = (unsigned short*)(ws + 0);          // 16.8 MB
    unsigned short* s_next = (unsigned short*)(ws + 16777216);
    unsigned short* Tf     = (unsigned short*)(ws + 33554432);
    unsigned short* Sf     = (unsigned short*)(ws + 50331648);
    unsigned short* Wtn_b  = (unsigned short*)(ws + 67108864);
    unsigned short* Wsn_b  = (unsigned short*)(ws + 67633152);
    unsigned short* Wt_b   = (unsigned short*)(ws + 68157440);
    unsigned short* Ws_b   = (unsigned short*)(ws + 69730304);
    float*          w_all  = (float*)(ws + 71303168);            // 512 KB

    convert_all<<<2048, 256, 0, stream>>>(W_tn, W_sn, W_t, W_s,
                                          Wtn_b, Wsn_b, Wt_b, Ws_b);

    gemm_next2<<<1024, 256, 0, stream>>>(T_t, S_t, Wtn_b, Wsn_b, b_tn, b_sn,
                                         t_next, s_next);

    dots_kernel<<<4096, 256, 0, stream>>>(s_att, t_spatial, t_next, s_next, w_all);

    fusion_kernel<<<4096, 256, 0, stream>>>(T_t, S_t, t_att, s_spatial,
                                            t_next, s_next, w_all, Tf, Sf);

    gemm_final<<<2048, 512, 0, stream>>>(Tf, Sf, Wt_b, Ws_b, b_t, b_s, out);
}